// Round 5
// baseline (1485.305 us; speedup 1.0000x reference)
//
#include <hip/hip_runtime.h>
#include <hip/hip_fp16.h>

typedef _Float16 f16;
typedef __attribute__((ext_vector_type(4))) _Float16 f16x4;
typedef __attribute__((ext_vector_type(8))) _Float16 f16x8;
typedef __attribute__((ext_vector_type(4))) float f32x4;

#define S_LEN 2048
#define D_MODEL 1024
#define N_HEADS 16
#define D_K 64
#define BATCH 4

// exp(-8): folded into mask so unnormalized P' = exp(score+rel-8)*mask stays small (f16-safe).
#define EXP_NEG8 3.35462627903e-4f

// ---------------- fp32 -> fp16 convert (vectorized) ----------------
__global__ void cvt_f32_f16(const float* __restrict__ src, f16* __restrict__ dst, int n4) {
  int i = blockIdx.x * blockDim.x + threadIdx.x;
  if (i < n4) {
    const float4 v = reinterpret_cast<const float4*>(src)[i];
    f16x4 h;
    h.x = (f16)v.x; h.y = (f16)v.y; h.z = (f16)v.z; h.w = (f16)v.w;
    reinterpret_cast<f16x4*>(dst)[i] = h;
  }
}

// ---------------- weight transpose + convert: WT[n][k] = (f16)W[k][n] ----------------
__global__ void wtrans(const float* __restrict__ W, f16* __restrict__ WT) {
  __shared__ float tile[32][33];
  const int n0 = blockIdx.x * 32, k0 = blockIdx.y * 32;
  const int tx = threadIdx.x, ty = threadIdx.y;  // block (32,8)
#pragma unroll
  for (int i = 0; i < 4; ++i)
    tile[ty + i * 8][tx] = W[(size_t)(k0 + ty + i * 8) * D_MODEL + n0 + tx];
  __syncthreads();
#pragma unroll
  for (int i = 0; i < 4; ++i)
    WT[(size_t)(n0 + ty + i * 8) * D_MODEL + k0 + tx] = (f16)tile[tx][ty + i * 8];
}

// ---------------- GEMM: C[8192][1024] = A(f16) @ W + bias, W given as WT[n][k] ----------------
template <int MODE>
__global__ __launch_bounds__(256) void gemm16(const f16* __restrict__ A, const f16* __restrict__ BT,
                                              const float* __restrict__ bias, void* __restrict__ outp) {
  __shared__ f16 As[128 * 40];
  __shared__ f16 Bs[128 * 40];
  const int t = threadIdx.x;
  const int lane = t & 63, wid = t >> 6;
  const int wm = wid >> 1, wn = wid & 1;
  const int lr = lane & 15, lg = lane >> 4;
  const int bm = blockIdx.y * 128, bn = blockIdx.x * 128;

  f32x4 acc[4][4] = {};

  const int r = t >> 2, kc = (t & 3) * 8;
  for (int k0 = 0; k0 < 1024; k0 += 32) {
    __syncthreads();
#pragma unroll
    for (int c = 0; c < 2; ++c) {
      const int row = r + c * 64;
      const int4 av = *reinterpret_cast<const int4*>(&A[(size_t)(bm + row) * 1024 + k0 + kc]);
      const int4 bv = *reinterpret_cast<const int4*>(&BT[(size_t)(bn + row) * 1024 + k0 + kc]);
      int2* ad = reinterpret_cast<int2*>(&As[row * 40 + kc]);
      ad[0] = make_int2(av.x, av.y);
      ad[1] = make_int2(av.z, av.w);
      int2* bd = reinterpret_cast<int2*>(&Bs[row * 40 + kc]);
      bd[0] = make_int2(bv.x, bv.y);
      bd[1] = make_int2(bv.z, bv.w);
    }
    __syncthreads();
#pragma unroll
    for (int kk = 0; kk < 2; ++kk) {
      f16x4 af[4], bf[4];
#pragma unroll
      for (int mf = 0; mf < 4; ++mf)
        af[mf] = *reinterpret_cast<const f16x4*>(&As[(wm * 64 + mf * 16 + lr) * 40 + kk * 16 + 4 * lg]);
#pragma unroll
      for (int nf = 0; nf < 4; ++nf)
        bf[nf] = *reinterpret_cast<const f16x4*>(&Bs[(wn * 64 + nf * 16 + lr) * 40 + kk * 16 + 4 * lg]);
#pragma unroll
      for (int mf = 0; mf < 4; ++mf)
#pragma unroll
        for (int nf = 0; nf < 4; ++nf)
          acc[mf][nf] = __builtin_amdgcn_mfma_f32_16x16x16f16(af[mf], bf[nf], acc[mf][nf], 0, 0, 0);
    }
  }

#pragma unroll
  for (int mf = 0; mf < 4; ++mf) {
#pragma unroll
    for (int nf = 0; nf < 4; ++nf) {
#pragma unroll
      for (int i = 0; i < 4; ++i) {
        const int mrow = bm + wm * 64 + mf * 16 + 4 * lg + i;
        const int ncol = bn + wn * 64 + nf * 16 + lr;
        const float v = acc[mf][nf][i] + bias[ncol];
        const int b = mrow >> 11, s = mrow & 2047;
        const int h = ncol >> 6, d = ncol & 63;
        if (MODE == 0) {
          ((f16*)outp)[((size_t)(b * N_HEADS + h) * S_LEN + s) * D_K + d] = (f16)(v * 0.125f);
        } else if (MODE == 1) {
          ((f16*)outp)[((size_t)(b * N_HEADS + h) * S_LEN + s) * D_K + d] = (f16)v;
        } else if (MODE == 2) {
          ((f16*)outp)[((size_t)(b * N_HEADS + h) * D_K + d) * S_LEN + s] = (f16)v;
        } else {
          ((float*)outp)[(size_t)mrow * D_MODEL + ncol] = v;
        }
      }
    }
  }
}

// ---------------- single-pass fused attention with deferred normalization ----------------
// sc = mfma(K, Q) transposed-score scheme: lane (lr,lg) holds q = r0+lr, k = c0+16j+4lg+i.
// One k-sweep computes sum, PV (unnormalized), and stores unnormalized P' (f16).
// ALL streams (K, V, rel) are register-prefetched one 64-k chunk ahead so no VMEM
// consumed in CH was issued later than a full chunk earlier (~32 loads in flight/wave).

template <bool B16> struct RelV { using type = f16x4; };
template <> struct RelV<false> { using type = float4; };

__device__ __forceinline__ float4 rel2f(const f16x4 v) {
  return make_float4((float)v[0], (float)v[1], (float)v[2], (float)v[3]);
}
__device__ __forceinline__ float4 rel2f(const float4 v) { return v; }

template <bool R16, bool PF16>
__global__ __launch_bounds__(256) void attn_single(const f16* __restrict__ qg, const f16* __restrict__ kg,
                                                   const f16* __restrict__ vTg, const void* __restrict__ relp,
                                                   const int* __restrict__ mask, float* __restrict__ attn_out,
                                                   f16* __restrict__ Pbuf, float* __restrict__ invb,
                                                   f16* __restrict__ ctx) {
  using RelT = typename RelV<R16>::type;
  const int b = blockIdx.x & 3, qt = blockIdx.x >> 2;
  const int h = blockIdx.y;
  const int t = threadIdx.x, w = t >> 6, lane = t & 63;
  const int lr = lane & 15, lg = lane >> 4;
  __shared__ float mask_f[S_LEN];

  for (int i = t; i < S_LEN; i += 256) mask_f[i] = mask[b * S_LEN + i] ? EXP_NEG8 : 0.f;
  __syncthreads();

  const size_t bh = (size_t)(b * N_HEADS + h);
  const f16* qbh = qg + bh * S_LEN * D_K;
  const f16* kbh = kg + bh * S_LEN * D_K;
  const f16* vbh = vTg + bh * (size_t)D_K * S_LEN;

  const int r0 = qt * 64 + w * 16;
  const int myq = r0 + lr;

  const f16* relq16 = (const f16*)relp + (size_t)h * S_LEN * S_LEN + (size_t)myq * S_LEN;
  const float* relq32 = (const float*)relp + (size_t)h * S_LEN * S_LEN + (size_t)myq * S_LEN;
  float* attnq = attn_out + bh * (size_t)S_LEN * S_LEN + (size_t)myq * S_LEN;
  f16* Pq = Pbuf + bh * (size_t)S_LEN * S_LEN + (size_t)myq * S_LEN;

  // Q fragments, permuted-k pairing: qf8[p] covers dk {32p + 8lg .. +7}
  f16x8 qf8[2];
#pragma unroll
  for (int p = 0; p < 2; ++p)
    qf8[p] = *reinterpret_cast<const f16x8*>(&qbh[(size_t)myq * D_K + 32 * p + 8 * lg]);

  // rel superchunk loader: rb[0..7] = chunks c0, c0+64; entry u -> col c0 + 64*(u>>2) + 16*(u&3) + 4lg
  auto LR = [&](RelT* rb, int c0) {
#pragma unroll
    for (int u = 0; u < 8; ++u) {
      const int col = c0 + (u >> 2) * 64 + (u & 3) * 16 + 4 * lg;
      if constexpr (R16)
        rb[u] = *reinterpret_cast<const f16x4*>(&relq16[col]);
      else
        rb[u] = *reinterpret_cast<const float4*>(&relq32[col]);
    }
  };
  // K chunk loader (8 x 16B, permuted-k): kb[2j+p] = K[c0+16j+lr][32p + 8lg ..+7]
  auto LK = [&](f16x8* kb, int c0) {
#pragma unroll
    for (int j = 0; j < 4; ++j) {
      kb[2 * j] = *reinterpret_cast<const f16x8*>(&kbh[(size_t)(c0 + 16 * j + lr) * D_K + 8 * lg]);
      kb[2 * j + 1] = *reinterpret_cast<const f16x8*>(&kbh[(size_t)(c0 + 16 * j + lr) * D_K + 32 + 8 * lg]);
    }
  };
  // V chunk loader (16 x 8B): vb[4j+nf] = V^T[nf*16+lr][c0+16j+4lg ..+3]
  auto LV = [&](f16x4* vb, int c0) {
#pragma unroll
    for (int j = 0; j < 4; ++j)
#pragma unroll
      for (int nf = 0; nf < 4; ++nf)
        vb[4 * j + nf] =
            *reinterpret_cast<const f16x4*>(&vbh[(size_t)(nf * 16 + lr) * S_LEN + c0 + 16 * j + 4 * lg]);
  };

  float sum = 0.f;
  f32x4 pv[4] = {};

  // compute one 64-k chunk: all of kb/vb/rb were loaded >= one chunk ago
  auto CH = [&](const f16x8* kb, const f16x4* vb, const RelT* rb, int c0) {
    f32x4 sc[4] = {};
#pragma unroll
    for (int p = 0; p < 2; ++p) {
      const f16x4 qlo = __builtin_shufflevector(qf8[p], qf8[p], 0, 1, 2, 3);
      const f16x4 qhi = __builtin_shufflevector(qf8[p], qf8[p], 4, 5, 6, 7);
#pragma unroll
      for (int j = 0; j < 4; ++j) {
        const f16x8 kv = kb[2 * j + p];
        sc[j] = __builtin_amdgcn_mfma_f32_16x16x16f16(
            __builtin_shufflevector(kv, kv, 0, 1, 2, 3), qlo, sc[j], 0, 0, 0);
        sc[j] = __builtin_amdgcn_mfma_f32_16x16x16f16(
            __builtin_shufflevector(kv, kv, 4, 5, 6, 7), qhi, sc[j], 0, 0, 0);
      }
    }
#pragma unroll
    for (int j = 0; j < 4; ++j) {
      const int col = c0 + 16 * j + 4 * lg;
      const float4 rl = rel2f(rb[j]);
      const float4 mk = *reinterpret_cast<const float4*>(&mask_f[col]);  // premultiplied exp(-8)
      const float a0 = __expf(sc[j][0] + rl.x) * mk.x;
      const float a1 = __expf(sc[j][1] + rl.y) * mk.y;
      const float a2 = __expf(sc[j][2] + rl.z) * mk.z;
      const float a3 = __expf(sc[j][3] + rl.w) * mk.w;
      sum += a0 + a1 + a2 + a3;
      f16x4 pf;
      pf.x = (f16)a0; pf.y = (f16)a1; pf.z = (f16)a2; pf.w = (f16)a3;
      if constexpr (PF16) {
        *reinterpret_cast<f16x4*>(&Pq[col]) = pf;
      } else {
        *reinterpret_cast<float4*>(&attnq[col]) = make_float4(a0, a1, a2, a3);
      }
#pragma unroll
      for (int nf = 0; nf < 4; ++nf)
        pv[nf] = __builtin_amdgcn_mfma_f32_16x16x16f16(pf, vb[4 * j + nf], pv[nf], 0, 0, 0);
    }
  };

  RelT rA[8], rB[8];
  f16x8 kA[8], kB[8];
  f16x4 vA[16], vB[16];
  LR(rA, 0);
  LK(kA, 0);
  LV(vA, 0);
#pragma unroll 1
  for (int s0 = 0; s0 < S_LEN; s0 += 256) {
    LR(rB, s0 + 128);  // rel 2-3 chunks ahead
    LK(kB, s0 + 64);
    LV(vB, s0 + 64);
    CH(kA, vA, rA, s0);
    LK(kA, s0 + 128);
    LV(vA, s0 + 128);
    CH(kB, vB, rA + 4, s0 + 64);
    if (s0 + 256 < S_LEN) LR(rA, s0 + 256);
    LK(kB, s0 + 192);
    LV(vB, s0 + 192);
    CH(kA, vA, rB, s0 + 128);
    if (s0 + 256 < S_LEN) {
      LK(kA, s0 + 256);
      LV(vA, s0 + 256);
    }
    CH(kB, vB, rB + 4, s0 + 192);
  }

  sum += __shfl_xor(sum, 16, 64);
  sum += __shfl_xor(sum, 32, 64);
  const float inv = 1.f / sum;  // lane holds inv for row myq = r0+lr

  // ctx write: pv[nf][i] belongs to q-row r0+4lg+i -> needs that row's inv
  float ivr[4];
#pragma unroll
  for (int i = 0; i < 4; ++i) ivr[i] = __shfl(inv, 4 * lg + i, 64);
#pragma unroll
  for (int nf = 0; nf < 4; ++nf)
#pragma unroll
    for (int i = 0; i < 4; ++i)
      ctx[(size_t)(b * S_LEN + r0 + 4 * lg + i) * D_MODEL + h * D_K + nf * 16 + lr] =
          (f16)(pv[nf][i] * ivr[i]);

  if constexpr (PF16) {
    if (lane < 16) invb[bh * S_LEN + r0 + lr] = inv;
  } else {
    // in-place rescale of this wave's 16 rows (f32 RMW)
    float4* aw4 = reinterpret_cast<float4*>(attn_out + bh * (size_t)S_LEN * S_LEN + (size_t)r0 * S_LEN);
#pragma unroll 1
    for (int it = 0; it < 128; it += 4) {
#pragma unroll
      for (int u = 0; u < 4; ++u) {
        const float iv = __shfl(inv, (it + u) >> 3, 64);
        float4 v = aw4[(it + u) * 64 + lane];
        v.x *= iv; v.y *= iv; v.z *= iv; v.w *= iv;
        aw4[(it + u) * 64 + lane] = v;
      }
    }
  }
}

// ---------------- normalize: attn = P'(f16) * inv[row], pure streaming ----------------
__global__ __launch_bounds__(256) void norm_attn(const f16* __restrict__ P, const float* __restrict__ invb,
                                                 float* __restrict__ attn) {
  const size_t total = (size_t)BATCH * N_HEADS * S_LEN * (S_LEN / 8);  // groups of 8
  size_t i = (size_t)blockIdx.x * 256 + threadIdx.x;
  const size_t stride = (size_t)gridDim.x * 256;
  for (; i < total; i += stride) {
    const f16x8 p = reinterpret_cast<const f16x8*>(P)[i];
    const float iv = invb[i >> 8];
    float4 o0 = make_float4((float)p[0] * iv, (float)p[1] * iv, (float)p[2] * iv, (float)p[3] * iv);
    float4 o1 = make_float4((float)p[4] * iv, (float)p[5] * iv, (float)p[6] * iv, (float)p[7] * iv);
    reinterpret_cast<float4*>(attn)[2 * i] = o0;
    reinterpret_cast<float4*>(attn)[2 * i + 1] = o1;
  }
}

extern "C" void kernel_launch(void* const* d_in, const int* in_sizes, int n_in,
                              void* d_out, int out_size, void* d_ws, size_t ws_size,
                              hipStream_t stream) {
  const float* Q    = (const float*)d_in[0];
  const float* K    = (const float*)d_in[1];
  const float* V    = (const float*)d_in[2];
  const int*   mask = (const int*)d_in[3];
  const float* rel  = (const float*)d_in[4];
  const float* Wq   = (const float*)d_in[5];
  const float* bq   = (const float*)d_in[6];
  const float* Wk   = (const float*)d_in[7];
  const float* bk   = (const float*)d_in[8];
  const float* Wv   = (const float*)d_in[9];
  const float* bv   = (const float*)d_in[10];
  const float* Wo   = (const float*)d_in[11];
  const float* bo   = (const float*)d_in[12];

  char* wsb = (char*)d_ws;
  const size_t XSZ = (size_t)BATCH * S_LEN * D_MODEL * sizeof(f16);  // 16.78 MB
  const size_t WSZ = (size_t)D_MODEL * D_MODEL * sizeof(f16);        // 2 MB
  f16* Qh  = (f16*)(wsb);
  f16* Kh  = (f16*)(wsb + XSZ);
  f16* Vh  = (f16*)(wsb + 2 * XSZ);
  f16* WqT = (f16*)(wsb + 3 * XSZ);
  f16* WkT = (f16*)(wsb + 3 * XSZ + WSZ);
  f16* WvT = (f16*)(wsb + 3 * XSZ + 2 * WSZ);
  f16* WoT = (f16*)(wsb + 3 * XSZ + 3 * WSZ);
  f16* qb  = (f16*)(wsb + 3 * XSZ + 4 * WSZ);
  f16* kb  = (f16*)(wsb + 4 * XSZ + 4 * WSZ);
  f16* vTb = (f16*)(wsb + 5 * XSZ + 4 * WSZ);
  f16* ctx = (f16*)(wsb + 6 * XSZ + 4 * WSZ);

  const size_t BASE  = 7 * XSZ + 4 * WSZ;                                        // 125,829,120
  const size_t RELSZ = (size_t)N_HEADS * S_LEN * S_LEN * sizeof(f16);            // 134,217,728
  const size_t PSZ   = (size_t)BATCH * N_HEADS * S_LEN * S_LEN * sizeof(f16);    // 536,870,912
  const size_t INVSZ = (size_t)BATCH * N_HEADS * S_LEN * sizeof(float);          // 524,288
  f16*   rel16 = (f16*)(wsb + BASE);
  f16*   Pbuf  = (f16*)(wsb + BASE + RELSZ);
  float* invb  = (float*)(wsb + BASE + RELSZ + PSZ);
  const bool r16  = ws_size >= BASE + RELSZ;
  const bool pf16 = ws_size >= BASE + RELSZ + PSZ + INVSZ;

  float* out0 = (float*)d_out;
  float* attn = out0 + (size_t)BATCH * S_LEN * D_MODEL;

  const int n4 = BATCH * S_LEN * D_MODEL / 4;  // 2097152
  cvt_f32_f16<<<dim3(n4 / 256), 256, 0, stream>>>(Q, Qh, n4);
  cvt_f32_f16<<<dim3(n4 / 256), 256, 0, stream>>>(K, Kh, n4);
  cvt_f32_f16<<<dim3(n4 / 256), 256, 0, stream>>>(V, Vh, n4);
  wtrans<<<dim3(32, 32), dim3(32, 8), 0, stream>>>(Wq, WqT);
  wtrans<<<dim3(32, 32), dim3(32, 8), 0, stream>>>(Wk, WkT);
  wtrans<<<dim3(32, 32), dim3(32, 8), 0, stream>>>(Wv, WvT);
  wtrans<<<dim3(32, 32), dim3(32, 8), 0, stream>>>(Wo, WoT);
  if (r16) {
    const int nr4 = N_HEADS * S_LEN * S_LEN / 4;  // 16,777,216
    cvt_f32_f16<<<dim3(nr4 / 256), 256, 0, stream>>>(rel, rel16, nr4);
  }

  gemm16<0><<<dim3(8, 64), 256, 0, stream>>>(Qh, WqT, bq, qb);
  gemm16<1><<<dim3(8, 64), 256, 0, stream>>>(Kh, WkT, bk, kb);
  gemm16<2><<<dim3(8, 64), 256, 0, stream>>>(Vh, WvT, bv, vTb);

  const dim3 agrid(BATCH * (S_LEN / 64), N_HEADS);
  if (pf16) {
    attn_single<true, true><<<agrid, 256, 0, stream>>>(qb, kb, vTb, rel16, mask, attn, Pbuf, invb, ctx);
    norm_attn<<<dim3(16384), 256, 0, stream>>>(Pbuf, invb, attn);
  } else if (r16) {
    attn_single<true, false><<<agrid, 256, 0, stream>>>(qb, kb, vTb, rel16, mask, attn, Pbuf, invb, ctx);
  } else {
    attn_single<false, false><<<agrid, 256, 0, stream>>>(qb, kb, vTb, rel, mask, attn, Pbuf, invb, ctx);
  }

  gemm16<3><<<dim3(8, 64), 256, 0, stream>>>(ctx, WoT, bo, (void*)out0);
}

// Round 6
// 970.900 us; speedup vs baseline: 1.5298x; 1.5298x over previous
//
#include <hip/hip_runtime.h>
#include <hip/hip_fp16.h>

typedef _Float16 f16;
typedef __attribute__((ext_vector_type(4))) _Float16 f16x4;
typedef __attribute__((ext_vector_type(8))) _Float16 f16x8;
typedef __attribute__((ext_vector_type(4))) float f32x4;

#define S_LEN 2048
#define D_MODEL 1024
#define N_HEADS 16
#define D_K 64
#define BATCH 4

// exp(-8): folded into mask so unnormalized P' = exp(score+rel-8)*mask stays small (f16-safe).
#define EXP_NEG8 3.35462627903e-4f

// ---------------- fp32 -> fp16 convert (vectorized) ----------------
__global__ void cvt_f32_f16(const float* __restrict__ src, f16* __restrict__ dst, int n4) {
  int i = blockIdx.x * blockDim.x + threadIdx.x;
  if (i < n4) {
    const float4 v = reinterpret_cast<const float4*>(src)[i];
    f16x4 h;
    h.x = (f16)v.x; h.y = (f16)v.y; h.z = (f16)v.z; h.w = (f16)v.w;
    reinterpret_cast<f16x4*>(dst)[i] = h;
  }
}

// ---------------- weight transpose + convert: WT[n][k] = (f16)W[k][n] ----------------
__global__ void wtrans(const float* __restrict__ W, f16* __restrict__ WT) {
  __shared__ float tile[32][33];
  const int n0 = blockIdx.x * 32, k0 = blockIdx.y * 32;
  const int tx = threadIdx.x, ty = threadIdx.y;  // block (32,8)
#pragma unroll
  for (int i = 0; i < 4; ++i)
    tile[ty + i * 8][tx] = W[(size_t)(k0 + ty + i * 8) * D_MODEL + n0 + tx];
  __syncthreads();
#pragma unroll
  for (int i = 0; i < 4; ++i)
    WT[(size_t)(n0 + ty + i * 8) * D_MODEL + k0 + tx] = (f16)tile[tx][ty + i * 8];
}

// ---------------- GEMM: C[8192][1024] = A(f16) @ W + bias, W given as WT[n][k] ----------------
template <int MODE>
__global__ __launch_bounds__(256) void gemm16(const f16* __restrict__ A, const f16* __restrict__ BT,
                                              const float* __restrict__ bias, void* __restrict__ outp) {
  __shared__ f16 As[128 * 40];
  __shared__ f16 Bs[128 * 40];
  const int t = threadIdx.x;
  const int lane = t & 63, wid = t >> 6;
  const int wm = wid >> 1, wn = wid & 1;
  const int lr = lane & 15, lg = lane >> 4;
  const int bm = blockIdx.y * 128, bn = blockIdx.x * 128;

  f32x4 acc[4][4] = {};

  const int r = t >> 2, kc = (t & 3) * 8;
  for (int k0 = 0; k0 < 1024; k0 += 32) {
    __syncthreads();
#pragma unroll
    for (int c = 0; c < 2; ++c) {
      const int row = r + c * 64;
      const int4 av = *reinterpret_cast<const int4*>(&A[(size_t)(bm + row) * 1024 + k0 + kc]);
      const int4 bv = *reinterpret_cast<const int4*>(&BT[(size_t)(bn + row) * 1024 + k0 + kc]);
      int2* ad = reinterpret_cast<int2*>(&As[row * 40 + kc]);
      ad[0] = make_int2(av.x, av.y);
      ad[1] = make_int2(av.z, av.w);
      int2* bd = reinterpret_cast<int2*>(&Bs[row * 40 + kc]);
      bd[0] = make_int2(bv.x, bv.y);
      bd[1] = make_int2(bv.z, bv.w);
    }
    __syncthreads();
#pragma unroll
    for (int kk = 0; kk < 2; ++kk) {
      f16x4 af[4], bf[4];
#pragma unroll
      for (int mf = 0; mf < 4; ++mf)
        af[mf] = *reinterpret_cast<const f16x4*>(&As[(wm * 64 + mf * 16 + lr) * 40 + kk * 16 + 4 * lg]);
#pragma unroll
      for (int nf = 0; nf < 4; ++nf)
        bf[nf] = *reinterpret_cast<const f16x4*>(&Bs[(wn * 64 + nf * 16 + lr) * 40 + kk * 16 + 4 * lg]);
#pragma unroll
      for (int mf = 0; mf < 4; ++mf)
#pragma unroll
        for (int nf = 0; nf < 4; ++nf)
          acc[mf][nf] = __builtin_amdgcn_mfma_f32_16x16x16f16(af[mf], bf[nf], acc[mf][nf], 0, 0, 0);
    }
  }

#pragma unroll
  for (int mf = 0; mf < 4; ++mf) {
#pragma unroll
    for (int nf = 0; nf < 4; ++nf) {
#pragma unroll
      for (int i = 0; i < 4; ++i) {
        const int mrow = bm + wm * 64 + mf * 16 + 4 * lg + i;
        const int ncol = bn + wn * 64 + nf * 16 + lr;
        const float v = acc[mf][nf][i] + bias[ncol];
        const int b = mrow >> 11, s = mrow & 2047;
        const int h = ncol >> 6, d = ncol & 63;
        if (MODE == 0) {
          ((f16*)outp)[((size_t)(b * N_HEADS + h) * S_LEN + s) * D_K + d] = (f16)(v * 0.125f);
        } else if (MODE == 1) {
          ((f16*)outp)[((size_t)(b * N_HEADS + h) * S_LEN + s) * D_K + d] = (f16)v;
        } else if (MODE == 2) {
          ((f16*)outp)[((size_t)(b * N_HEADS + h) * D_K + d) * S_LEN + s] = (f16)v;
        } else {
          ((float*)outp)[(size_t)mrow * D_MODEL + ncol] = v;
        }
      }
    }
  }
}

// ---------------- staged single-pass fused attention (T3 2-phase, LDS double-buffer) ----------------
// Per block: 64 q-rows, sweep kv in 64-chunks. Per chunk:
//   STAGE(next): 6x16B global loads/wave -> regs (issued FIRST, land during compute)
//   CH(cur): ds_read K/V/rel (XOR-swizzled, conflict-free) -> MFMA + exp + P' store + PV
//   ds_write staged regs -> LDS[next]; __syncthreads.
// K/V loaded once per block (was 4x per-wave). Swizzles:
//   K : LDS[row][cg']  cg' = cg ^ (row&7)        (16B groups, cg = d>>3)
//   V : LDS[d][sg']    sg' = sg ^ (2*(d&7))      (8B groups,  sg = s>>2)
//   rel:LDS[q][sg']    sg' = sg ^ (2*(q&7))
__global__ __launch_bounds__(256) void attn_staged(const f16* __restrict__ qg, const f16* __restrict__ kg,
                                                   const f16* __restrict__ vTg, const f16* __restrict__ rel16,
                                                   const int* __restrict__ mask, f16* __restrict__ Pbuf,
                                                   float* __restrict__ invb, f16* __restrict__ ctx) {
  const int b = blockIdx.x & 3, qt = blockIdx.x >> 2;
  const int h = blockIdx.y;
  const int t = threadIdx.x, w = t >> 6, lane = t & 63;
  const int lr = lane & 15, lg = lane >> 4;
  const int lr7 = lr & 7;
  const int Ld8 = lane >> 3, Lm8 = lane & 7;

  __shared__ f16 Kc[2][64 * 64];
  __shared__ f16 Vc[2][64 * 64];
  __shared__ f16 Rc[2][64 * 64];
  __shared__ float mask_f[S_LEN];

  for (int i = t; i < S_LEN; i += 256) mask_f[i] = mask[b * S_LEN + i] ? EXP_NEG8 : 0.f;

  const size_t bh = (size_t)(b * N_HEADS + h);
  const f16* qbh = qg + bh * S_LEN * D_K;
  const f16* kbh = kg + bh * S_LEN * D_K;
  const f16* vbh = vTg + bh * (size_t)D_K * S_LEN;
  const f16* relh = rel16 + (size_t)h * S_LEN * S_LEN;

  const int r0 = qt * 64 + w * 16;
  const int myq = r0 + lr;
  f16* Pq = Pbuf + bh * (size_t)S_LEN * S_LEN + (size_t)myq * S_LEN;

  // staging rows (tile-local); row&7 == Ld8 for both
  const int row0 = w * 16 + Ld8;
  const int row1 = row0 + 8;
  // chunk-invariant global bases (linear, coalesced 16B/lane)
  const f16* gK0 = kbh + (size_t)row0 * D_K + Lm8 * 8;
  const f16* gK1 = kbh + (size_t)row1 * D_K + Lm8 * 8;
  const f16* gV0 = vbh + (size_t)row0 * S_LEN + Lm8 * 8;
  const f16* gV1 = vbh + (size_t)row1 * S_LEN + Lm8 * 8;
  const f16* gR0 = relh + (size_t)(qt * 64 + row0) * S_LEN + Lm8 * 8;
  const f16* gR1 = relh + (size_t)(qt * 64 + row1) * S_LEN + Lm8 * 8;
  // swizzled LDS dests (f16 idx)
  const int dK0 = row0 * 64 + ((Lm8 ^ Ld8) << 3);
  const int dK1 = row1 * 64 + ((Lm8 ^ Ld8) << 3);
  const int dVR0 = row0 * 64 + ((((Lm8 << 1) ^ (Ld8 << 1)) & 15) << 2);
  const int dVR1 = row1 * 64 + ((((Lm8 << 1) ^ (Ld8 << 1)) & 15) << 2);

  // Q fragments: qf8[p] covers dk {32p + 8lg .. +7}
  f16x8 qf8[2];
#pragma unroll
  for (int p = 0; p < 2; ++p)
    qf8[p] = *reinterpret_cast<const f16x8*>(&qbh[(size_t)myq * D_K + 32 * p + 8 * lg]);

  float sum = 0.f;
  f32x4 pv[4] = {};

  int4 sK0, sK1, sV0, sV1, sR0, sR1;

  auto GLOAD = [&](int c0) {
    sK0 = *reinterpret_cast<const int4*>(gK0 + (size_t)c0 * D_K);
    sK1 = *reinterpret_cast<const int4*>(gK1 + (size_t)c0 * D_K);
    sV0 = *reinterpret_cast<const int4*>(gV0 + c0);
    sV1 = *reinterpret_cast<const int4*>(gV1 + c0);
    sR0 = *reinterpret_cast<const int4*>(gR0 + c0);
    sR1 = *reinterpret_cast<const int4*>(gR1 + c0);
  };
  auto DSW = [&](int bb) {
    *reinterpret_cast<int4*>(&Kc[bb][dK0]) = sK0;
    *reinterpret_cast<int4*>(&Kc[bb][dK1]) = sK1;
    *reinterpret_cast<int4*>(&Vc[bb][dVR0]) = sV0;
    *reinterpret_cast<int4*>(&Vc[bb][dVR1]) = sV1;
    *reinterpret_cast<int4*>(&Rc[bb][dVR0]) = sR0;
    *reinterpret_cast<int4*>(&Rc[bb][dVR1]) = sR1;
  };

  auto CH = [&](int bb, int c0) {
    f32x4 sc[4] = {};
#pragma unroll
    for (int p = 0; p < 2; ++p) {
      const f16x4 qlo = __builtin_shufflevector(qf8[p], qf8[p], 0, 1, 2, 3);
      const f16x4 qhi = __builtin_shufflevector(qf8[p], qf8[p], 4, 5, 6, 7);
#pragma unroll
      for (int j = 0; j < 4; ++j) {
        const f16x8 kv = *reinterpret_cast<const f16x8*>(
            &Kc[bb][(16 * j + lr) * 64 + (((4 * p + lg) ^ lr7) << 3)]);
        sc[j] = __builtin_amdgcn_mfma_f32_16x16x16f16(
            __builtin_shufflevector(kv, kv, 0, 1, 2, 3), qlo, sc[j], 0, 0, 0);
        sc[j] = __builtin_amdgcn_mfma_f32_16x16x16f16(
            __builtin_shufflevector(kv, kv, 4, 5, 6, 7), qhi, sc[j], 0, 0, 0);
      }
    }
#pragma unroll
    for (int j = 0; j < 4; ++j) {
      const int sgp = ((4 * j + lg) ^ (lr7 << 1)) & 15;
      const f16x4 rl = *reinterpret_cast<const f16x4*>(&Rc[bb][(w * 16 + lr) * 64 + (sgp << 2)]);
      const int col = c0 + 16 * j + 4 * lg;
      const float4 mk = *reinterpret_cast<const float4*>(&mask_f[col]);  // broadcast, premult exp(-8)
      const float a0 = __expf(sc[j][0] + (float)rl[0]) * mk.x;
      const float a1 = __expf(sc[j][1] + (float)rl[1]) * mk.y;
      const float a2 = __expf(sc[j][2] + (float)rl[2]) * mk.z;
      const float a3 = __expf(sc[j][3] + (float)rl[3]) * mk.w;
      sum += a0 + a1 + a2 + a3;
      f16x4 pf;
      pf.x = (f16)a0; pf.y = (f16)a1; pf.z = (f16)a2; pf.w = (f16)a3;
      *reinterpret_cast<f16x4*>(&Pq[col]) = pf;
#pragma unroll
      for (int nf = 0; nf < 4; ++nf) {
        const f16x4 vf = *reinterpret_cast<const f16x4*>(&Vc[bb][(nf * 16 + lr) * 64 + (sgp << 2)]);
        pv[nf] = __builtin_amdgcn_mfma_f32_16x16x16f16(pf, vf, pv[nf], 0, 0, 0);
      }
    }
  };

  // prologue: fill buffer 0 (barrier also covers mask_f)
  GLOAD(0);
  DSW(0);
  __syncthreads();

#pragma unroll 1
  for (int c = 0; c < 32; ++c) {
    if (c < 31) GLOAD((c + 1) * 64);   // issue next-chunk loads FIRST (land during CH)
    CH(c & 1, c * 64);
    if (c < 31) DSW((c + 1) & 1);      // write-late (T14)
    __syncthreads();
  }

  sum += __shfl_xor(sum, 16, 64);
  sum += __shfl_xor(sum, 32, 64);
  const float inv = 1.f / sum;  // lane holds inv for row myq

  float ivr[4];
#pragma unroll
  for (int i = 0; i < 4; ++i) ivr[i] = __shfl(inv, 4 * lg + i, 64);
#pragma unroll
  for (int nf = 0; nf < 4; ++nf)
#pragma unroll
    for (int i = 0; i < 4; ++i)
      ctx[(size_t)(b * S_LEN + r0 + 4 * lg + i) * D_MODEL + h * D_K + nf * 16 + lr] =
          (f16)(pv[nf][i] * ivr[i]);

  if (lane < 16) invb[bh * S_LEN + r0 + lr] = inv;
}

// ---------------- fallback: register-prefetch single-pass (used only if ws too small) ----------------
template <bool B16> struct RelV { using type = f16x4; };
template <> struct RelV<false> { using type = float4; };

__device__ __forceinline__ float4 rel2f(const f16x4 v) {
  return make_float4((float)v[0], (float)v[1], (float)v[2], (float)v[3]);
}
__device__ __forceinline__ float4 rel2f(const float4 v) { return v; }

template <bool R16, bool PF16>
__global__ __launch_bounds__(256) void attn_single(const f16* __restrict__ qg, const f16* __restrict__ kg,
                                                   const f16* __restrict__ vTg, const void* __restrict__ relp,
                                                   const int* __restrict__ mask, float* __restrict__ attn_out,
                                                   f16* __restrict__ Pbuf, float* __restrict__ invb,
                                                   f16* __restrict__ ctx) {
  using RelT = typename RelV<R16>::type;
  const int b = blockIdx.x & 3, qt = blockIdx.x >> 2;
  const int h = blockIdx.y;
  const int t = threadIdx.x, w = t >> 6, lane = t & 63;
  const int lr = lane & 15, lg = lane >> 4;
  __shared__ float mask_f[S_LEN];

  for (int i = t; i < S_LEN; i += 256) mask_f[i] = mask[b * S_LEN + i] ? EXP_NEG8 : 0.f;
  __syncthreads();

  const size_t bh = (size_t)(b * N_HEADS + h);
  const f16* qbh = qg + bh * S_LEN * D_K;
  const f16* kbh = kg + bh * S_LEN * D_K;
  const f16* vbh = vTg + bh * (size_t)D_K * S_LEN;

  const int r0 = qt * 64 + w * 16;
  const int myq = r0 + lr;

  const f16* relq16 = (const f16*)relp + (size_t)h * S_LEN * S_LEN + (size_t)myq * S_LEN;
  const float* relq32 = (const float*)relp + (size_t)h * S_LEN * S_LEN + (size_t)myq * S_LEN;
  float* attnq = attn_out + bh * (size_t)S_LEN * S_LEN + (size_t)myq * S_LEN;
  f16* Pq = Pbuf + bh * (size_t)S_LEN * S_LEN + (size_t)myq * S_LEN;

  f16x8 qf8[2];
#pragma unroll
  for (int p = 0; p < 2; ++p)
    qf8[p] = *reinterpret_cast<const f16x8*>(&qbh[(size_t)myq * D_K + 32 * p + 8 * lg]);

  float sum = 0.f;
  f32x4 pv[4] = {};

  auto CH = [&](int c0) {
    f32x4 sc[4] = {};
#pragma unroll
    for (int p = 0; p < 2; ++p) {
      const f16x4 qlo = __builtin_shufflevector(qf8[p], qf8[p], 0, 1, 2, 3);
      const f16x4 qhi = __builtin_shufflevector(qf8[p], qf8[p], 4, 5, 6, 7);
#pragma unroll
      for (int j = 0; j < 4; ++j) {
        const f16x8 kv = *reinterpret_cast<const f16x8*>(
            &kbh[(size_t)(c0 + 16 * j + lr) * D_K + 32 * p + 8 * lg]);
        sc[j] = __builtin_amdgcn_mfma_f32_16x16x16f16(
            __builtin_shufflevector(kv, kv, 0, 1, 2, 3), qlo, sc[j], 0, 0, 0);
        sc[j] = __builtin_amdgcn_mfma_f32_16x16x16f16(
            __builtin_shufflevector(kv, kv, 4, 5, 6, 7), qhi, sc[j], 0, 0, 0);
      }
    }
#pragma unroll
    for (int j = 0; j < 4; ++j) {
      const int col = c0 + 16 * j + 4 * lg;
      float4 rl;
      if constexpr (R16)
        rl = rel2f(*reinterpret_cast<const f16x4*>(&relq16[col]));
      else
        rl = *reinterpret_cast<const float4*>(&relq32[col]);
      const float4 mk = *reinterpret_cast<const float4*>(&mask_f[col]);
      const float a0 = __expf(sc[j][0] + rl.x) * mk.x;
      const float a1 = __expf(sc[j][1] + rl.y) * mk.y;
      const float a2 = __expf(sc[j][2] + rl.z) * mk.z;
      const float a3 = __expf(sc[j][3] + rl.w) * mk.w;
      sum += a0 + a1 + a2 + a3;
      f16x4 pf;
      pf.x = (f16)a0; pf.y = (f16)a1; pf.z = (f16)a2; pf.w = (f16)a3;
      if constexpr (PF16) {
        *reinterpret_cast<f16x4*>(&Pq[col]) = pf;
      } else {
        *reinterpret_cast<float4*>(&attnq[col]) = make_float4(a0, a1, a2, a3);
      }
#pragma unroll
      for (int nf = 0; nf < 4; ++nf) {
        const f16x4 vf = *reinterpret_cast<const f16x4*>(&vbh[(size_t)(nf * 16 + lr) * S_LEN + col]);
        pv[nf] = __builtin_amdgcn_mfma_f32_16x16x16f16(pf, vf, pv[nf], 0, 0, 0);
      }
    }
  };

#pragma unroll 1
  for (int c0 = 0; c0 < S_LEN; c0 += 64) CH(c0);

  sum += __shfl_xor(sum, 16, 64);
  sum += __shfl_xor(sum, 32, 64);
  const float inv = 1.f / sum;

  float ivr[4];
#pragma unroll
  for (int i = 0; i < 4; ++i) ivr[i] = __shfl(inv, 4 * lg + i, 64);
#pragma unroll
  for (int nf = 0; nf < 4; ++nf)
#pragma unroll
    for (int i = 0; i < 4; ++i)
      ctx[(size_t)(b * S_LEN + r0 + 4 * lg + i) * D_MODEL + h * D_K + nf * 16 + lr] =
          (f16)(pv[nf][i] * ivr[i]);

  if constexpr (PF16) {
    if (lane < 16) invb[bh * S_LEN + r0 + lr] = inv;
  } else {
    float4* aw4 = reinterpret_cast<float4*>(attn_out + bh * (size_t)S_LEN * S_LEN + (size_t)r0 * S_LEN);
#pragma unroll 1
    for (int it = 0; it < 128; it += 4) {
#pragma unroll
      for (int u = 0; u < 4; ++u) {
        const float iv = __shfl(inv, (it + u) >> 3, 64);
        float4 v = aw4[(it + u) * 64 + lane];
        v.x *= iv; v.y *= iv; v.z *= iv; v.w *= iv;
        aw4[(it + u) * 64 + lane] = v;
      }
    }
  }
}

// ---------------- normalize: attn = P'(f16) * inv[row], pure streaming ----------------
__global__ __launch_bounds__(256) void norm_attn(const f16* __restrict__ P, const float* __restrict__ invb,
                                                 float* __restrict__ attn) {
  const size_t total = (size_t)BATCH * N_HEADS * S_LEN * (S_LEN / 8);  // groups of 8
  size_t i = (size_t)blockIdx.x * 256 + threadIdx.x;
  const size_t stride = (size_t)gridDim.x * 256;
  for (; i < total; i += stride) {
    const f16x8 p = reinterpret_cast<const f16x8*>(P)[i];
    const float iv = invb[i >> 8];
    float4 o0 = make_float4((float)p[0] * iv, (float)p[1] * iv, (float)p[2] * iv, (float)p[3] * iv);
    float4 o1 = make_float4((float)p[4] * iv, (float)p[5] * iv, (float)p[6] * iv, (float)p[7] * iv);
    reinterpret_cast<float4*>(attn)[2 * i] = o0;
    reinterpret_cast<float4*>(attn)[2 * i + 1] = o1;
  }
}

extern "C" void kernel_launch(void* const* d_in, const int* in_sizes, int n_in,
                              void* d_out, int out_size, void* d_ws, size_t ws_size,
                              hipStream_t stream) {
  const float* Q    = (const float*)d_in[0];
  const float* K    = (const float*)d_in[1];
  const float* V    = (const float*)d_in[2];
  const int*   mask = (const int*)d_in[3];
  const float* rel  = (const float*)d_in[4];
  const float* Wq   = (const float*)d_in[5];
  const float* bq   = (const float*)d_in[6];
  const float* Wk   = (const float*)d_in[7];
  const float* bk   = (const float*)d_in[8];
  const float* Wv   = (const float*)d_in[9];
  const float* bv   = (const float*)d_in[10];
  const float* Wo   = (const float*)d_in[11];
  const float* bo   = (const float*)d_in[12];

  char* wsb = (char*)d_ws;
  const size_t XSZ = (size_t)BATCH * S_LEN * D_MODEL * sizeof(f16);  // 16.78 MB
  const size_t WSZ = (size_t)D_MODEL * D_MODEL * sizeof(f16);        // 2 MB
  f16* Qh  = (f16*)(wsb);
  f16* Kh  = (f16*)(wsb + XSZ);
  f16* Vh  = (f16*)(wsb + 2 * XSZ);
  f16* WqT = (f16*)(wsb + 3 * XSZ);
  f16* WkT = (f16*)(wsb + 3 * XSZ + WSZ);
  f16* WvT = (f16*)(wsb + 3 * XSZ + 2 * WSZ);
  f16* WoT = (f16*)(wsb + 3 * XSZ + 3 * WSZ);
  f16* qb  = (f16*)(wsb + 3 * XSZ + 4 * WSZ);
  f16* kb  = (f16*)(wsb + 4 * XSZ + 4 * WSZ);
  f16* vTb = (f16*)(wsb + 5 * XSZ + 4 * WSZ);
  f16* ctx = (f16*)(wsb + 6 * XSZ + 4 * WSZ);

  const size_t BASE  = 7 * XSZ + 4 * WSZ;                                        // 125,829,120
  const size_t RELSZ = (size_t)N_HEADS * S_LEN * S_LEN * sizeof(f16);            // 134,217,728
  const size_t PSZ   = (size_t)BATCH * N_HEADS * S_LEN * S_LEN * sizeof(f16);    // 536,870,912
  const size_t INVSZ = (size_t)BATCH * N_HEADS * S_LEN * sizeof(float);          // 524,288
  f16*   rel16 = (f16*)(wsb + BASE);
  f16*   Pbuf  = (f16*)(wsb + BASE + RELSZ);
  float* invb  = (float*)(wsb + BASE + RELSZ + PSZ);
  const bool r16  = ws_size >= BASE + RELSZ;
  const bool pf16 = ws_size >= BASE + RELSZ + PSZ + INVSZ;

  float* out0 = (float*)d_out;
  float* attn = out0 + (size_t)BATCH * S_LEN * D_MODEL;

  const int n4 = BATCH * S_LEN * D_MODEL / 4;  // 2097152
  cvt_f32_f16<<<dim3(n4 / 256), 256, 0, stream>>>(Q, Qh, n4);
  cvt_f32_f16<<<dim3(n4 / 256), 256, 0, stream>>>(K, Kh, n4);
  cvt_f32_f16<<<dim3(n4 / 256), 256, 0, stream>>>(V, Vh, n4);
  wtrans<<<dim3(32, 32), dim3(32, 8), 0, stream>>>(Wq, WqT);
  wtrans<<<dim3(32, 32), dim3(32, 8), 0, stream>>>(Wk, WkT);
  wtrans<<<dim3(32, 32), dim3(32, 8), 0, stream>>>(Wv, WvT);
  wtrans<<<dim3(32, 32), dim3(32, 8), 0, stream>>>(Wo, WoT);
  if (r16) {
    const int nr4 = N_HEADS * S_LEN * S_LEN / 4;  // 16,777,216
    cvt_f32_f16<<<dim3(nr4 / 256), 256, 0, stream>>>(rel, rel16, nr4);
  }

  gemm16<0><<<dim3(8, 64), 256, 0, stream>>>(Qh, WqT, bq, qb);
  gemm16<1><<<dim3(8, 64), 256, 0, stream>>>(Kh, WkT, bk, kb);
  gemm16<2><<<dim3(8, 64), 256, 0, stream>>>(Vh, WvT, bv, vTb);

  const dim3 agrid(BATCH * (S_LEN / 64), N_HEADS);
  if (pf16) {
    attn_staged<<<agrid, 256, 0, stream>>>(qb, kb, vTb, rel16, mask, Pbuf, invb, ctx);
    norm_attn<<<dim3(16384), 256, 0, stream>>>(Pbuf, invb, attn);
  } else if (r16) {
    attn_single<true, false><<<agrid, 256, 0, stream>>>(qb, kb, vTb, rel16, mask, attn, Pbuf, invb, ctx);
  } else {
    attn_single<false, false><<<agrid, 256, 0, stream>>>(qb, kb, vTb, rel, mask, attn, Pbuf, invb, ctx);
  }

  gemm16<3><<<dim3(8, 64), 256, 0, stream>>>(ctx, WoT, bo, (void*)out0);
}